// Round 5
// baseline (782.318 us; speedup 1.0000x reference)
//
#include <hip/hip_runtime.h>
#include <stdint.h>

// ---------------------------------------------------------------------------
// SPP: out[n] = b + W @ [mean0(b) | mean2(s2) | mean4(s4) | mean8(s8)]
// v5: = v4 with the nontemporal-store compile fix (ext_vector_type for k_zero).
//     custom fast zero kernel (rocclr fill was 0.57 TB/s = 244us serial),
//     bf16 pk-atomic scatter -> bf16 pyramid (pre-scaled means for 0/4/8) ->
//     fused MFMA gather-GEMM, 512-thr blocks @ VGPR<=128, NT output stores.
// ---------------------------------------------------------------------------

#define N_PTS   1048576
#define NB      4
#define N2SEG   (NB*64*64*64)   // 1,048,576
#define N4SEG   (NB*32*32*32)   // 131,072
#define N8SEG   (NB*16*16*16)   // 16,384

typedef unsigned int uint;

// workspace offsets (bytes)
#define OFF_SUMS2  ((size_t)0)            // N2SEG*64 bf16 = 134,217,728
#define OFF_CNT2   ((size_t)134217728)    // N2SEG u32     =   4,194,304
#define OFF_SUMS0F ((size_t)138412032)    // 256 f32 (pad 1024)
#define MEMSET_END ((size_t)138413056)    // zeroed region (16B-multiple)
#define OFF_SUMS4  ((size_t)138413056)    // N4SEG*64 bf16 =  16,777,216
#define OFF_MEAN4  ((size_t)155190272)    // N4SEG*64 bf16 =  16,777,216
#define OFF_CNT4   ((size_t)171967488)    // N4SEG u32     =     524,288
#define OFF_SUMS8  ((size_t)172491776)    // N8SEG*64 bf16 =   2,097,152
#define OFF_MEAN8  ((size_t)174588928)    // N8SEG*64 bf16 =   2,097,152
#define OFF_CNT8   ((size_t)176686080)    // N8SEG u32     =      65,536
#define OFF_MEAN0  ((size_t)176751616)    // 4*32 u32 (pad 1024)
#define OFF_WF     ((size_t)176752640)    // 48 KB frag-ready W
#define WS_NEEDED  ((size_t)176801792)

typedef short s8v __attribute__((ext_vector_type(8)));   // 8 bf16 (4 VGPR)
typedef float f4v __attribute__((ext_vector_type(4)));   // MFMA C/D
typedef uint  u4v __attribute__((ext_vector_type(4)));   // NT-store-friendly

__device__ __forceinline__ uint pack_bf16x2(float a, float b) {
  uint ua = __float_as_uint(a), ub = __float_as_uint(b);
  ua = (ua + 0x7fffu + ((ua >> 16) & 1u)) >> 16;   // RNE
  ub = (ub + 0x7fffu + ((ub >> 16) & 1u)) >> 16;
  return (ub << 16) | ua;
}
__device__ __forceinline__ float bflo(uint u) { return __uint_as_float(u << 16); }
__device__ __forceinline__ float bfhi(uint u) { return __uint_as_float(u & 0xffff0000u); }

__device__ __forceinline__ uint scale_pk(uint u, float rc) {
  return pack_bf16x2(bflo(u) * rc, bfhi(u) * rc);
}

// ---- fast zero of the atomic-accumulated region (16B granularity)
#define ZERO_U4 (MEMSET_END / 16)         // 8,650,816 x 16B
__global__ __launch_bounds__(256) void k_zero(u4v* __restrict__ p) {
  u4v z = (u4v)0u;
  size_t stride = (size_t)gridDim.x * 256;
  for (size_t i = blockIdx.x * 256ull + threadIdx.x; i < ZERO_U4; i += stride)
    __builtin_nontemporal_store(z, &p[i]);
}

// ---- frag-ready W: Wf[((kt*6+nt)*64+l)*4+d] = pack(W[n][k], W[n][k+1])
//      n = nt*16+(l&15), k = kt*32+(l>>4)*8+2d   (B[k][n] = W[n][k])
__global__ __launch_bounds__(256) void k_wf(const float* __restrict__ W,
                                            uint* __restrict__ Wf) {
  int idx = blockIdx.x * 256 + threadIdx.x;        // < 12288
  int d = idx & 3, l = (idx >> 2) & 63, ktnt = idx >> 8;
  int kt = ktnt / 6, nt = ktnt - kt * 6;
  int n = nt * 16 + (l & 15);
  int k = kt * 32 + (l >> 4) * 8 + d * 2;
  Wf[idx] = pack_bf16x2(W[n * 256 + k], W[n * 256 + k + 1]);
}

// ---- scatter: 2 points per wave, lane = (half, channel-pair), pk-bf16 atomics
__global__ __launch_bounds__(256) void k_scatter2(
    const float* __restrict__ feats, const int* __restrict__ coords,
    const int* __restrict__ batch, uint* __restrict__ sums2,
    uint* __restrict__ cnt2)
{
  int l = threadIdx.x & 63;
  int c2 = l & 31, half = l >> 5;
  int wid = (blockIdx.x * 256 + threadIdx.x) >> 6;
  int nw = (gridDim.x * 256) >> 6;
  for (int p0 = wid * 2; p0 < N_PTS; p0 += nw * 2) {
    int p = p0 + half;
    float2 f = ((const float2*)feats)[(size_t)p * 32 + c2];
    int b = batch[p];
    int x = coords[3 * p], y = coords[3 * p + 1], z = coords[3 * p + 2];
    int s2 = ((b * 64 + (x >> 1)) * 64 + (y >> 1)) * 64 + (z >> 1);
    uint pk = pack_bf16x2(f.x, f.y);
    uint64_t addr = (uint64_t)(uintptr_t)(sums2 + (size_t)s2 * 32 + c2);
    asm volatile("global_atomic_pk_add_bf16 %0, %1, off"
                 :: "v"(addr), "v"(pk) : "memory");
    if (c2 == 0) atomicAdd(&cnt2[s2], 1u);
  }
}

// ---- 8-child tree reduction; writes raw sums (next level), pre-scaled mean,
//      and cnt. thread = (sc, c2)
__global__ __launch_bounds__(256) void k_down_bf(
    const uint* __restrict__ sumsF, const uint* __restrict__ cntF,
    uint* __restrict__ sumsC, uint* __restrict__ meanC,
    uint* __restrict__ cntC, int lgC, int nC)
{
  int tid = blockIdx.x * 256 + threadIdx.x;
  int sc = tid >> 5, c2 = tid & 31;
  if (sc >= nC) return;
  int CG = 1 << lgC, FG = CG << 1;
  int b = sc >> (3 * lgC);
  int r = sc & ((1 << (3 * lgC)) - 1);
  int x = r >> (2 * lgC), y = (r >> lgC) & (CG - 1), z = r & (CG - 1);
  float sx = 0.f, sy = 0.f;
  uint cn = 0;
  #pragma unroll
  for (int dx = 0; dx < 2; ++dx)
    #pragma unroll
    for (int dy = 0; dy < 2; ++dy)
      #pragma unroll
      for (int dz = 0; dz < 2; ++dz) {
        int sf = ((b * FG + 2 * x + dx) * FG + (2 * y + dy)) * FG + (2 * z + dz);
        uint u = sumsF[(size_t)sf * 32 + c2];
        sx += bflo(u); sy += bfhi(u);
        cn += cntF[sf];                       // same addr across 32 lanes: L1 broadcast
      }
  sumsC[(size_t)sc * 32 + c2] = pack_bf16x2(sx, sy);
  float rc = 1.0f / (float)(cn > 1u ? cn : 1u);
  meanC[(size_t)sc * 32 + c2] = pack_bf16x2(sx * rc, sy * rc);
  if (c2 == 0) cntC[sc] = cn;
}

// ---- per-batch global partial reduce (32 blocks/batch), f32 atomics
__global__ __launch_bounds__(256) void k_gpart(
    const uint* __restrict__ sums8, float* __restrict__ sums0f)
{
  __shared__ float2 red[8][32];
  int b = blockIdx.x >> 5, chunk = blockIdx.x & 31;
  int t = threadIdx.x, c2 = t & 31, g = t >> 5;
  float sx = 0.f, sy = 0.f;
  for (int i = g; i < 128; i += 8) {
    uint u = sums8[(size_t)(b * 4096 + chunk * 128 + i) * 32 + c2];
    sx += bflo(u); sy += bfhi(u);
  }
  red[g][c2] = make_float2(sx, sy);
  __syncthreads();
  if (g == 0) {
    float ax = 0.f, ay = 0.f;
    #pragma unroll
    for (int i = 0; i < 8; ++i) { ax += red[i][c2].x; ay += red[i][c2].y; }
    unsafeAtomicAdd(&sums0f[b * 64 + 2 * c2], ax);
    unsafeAtomicAdd(&sums0f[b * 64 + 2 * c2 + 1], ay);
  }
}

// ---- finalize level 0: cnt0 from cnt8, mean0 = sums0f/cnt0 (bf16, pre-scaled)
__global__ __launch_bounds__(256) void k_fin0(
    const float* __restrict__ sums0f, const uint* __restrict__ cnt8,
    uint* __restrict__ mean0)
{
  __shared__ uint redc[256];
  __shared__ float rcs[NB];
  int t = threadIdx.x;
  uint cn = 0;
  for (int i = 0; i < 64; ++i) cn += cnt8[t * 64 + i];
  redc[t] = cn;
  __syncthreads();
  if (t < NB) {
    uint s = 0;
    for (int i = 0; i < 64; ++i) s += redc[t * 64 + i];
    rcs[t] = 1.0f / (float)(s > 1u ? s : 1u);
  }
  __syncthreads();
  if (t < 128) {
    int b = t >> 5, c2 = t & 31;
    float rc = rcs[b];
    mean0[b * 32 + c2] =
        pack_bf16x2(sums0f[b * 64 + 2 * c2] * rc, sums0f[b * 64 + 2 * c2 + 1] * rc);
  }
}

// ---- fused gather-GEMM: wave = 16 points; A gathered (level-2 scaled
//      in-register, others pre-scaled); B frag-ready in LDS; acc[6] only.
//      512-thr blocks, VGPR<=128 -> 4 waves/SIMD, 2 blocks/CU (96KB LDS).
#define GPB 8
__global__ __launch_bounds__(512, 4) void k_final(
    const int* __restrict__ coords, const int* __restrict__ batch,
    const uint* __restrict__ mean0,
    const uint* __restrict__ sums2, const uint* __restrict__ cnt2,
    const uint* __restrict__ mean4, const uint* __restrict__ mean8,
    const uint4* __restrict__ Wf, const float* __restrict__ bias,
    float* __restrict__ out)
{
  __shared__ uint4 wf[3072];   // 48 KB frag-ready W
  int t = threadIdx.x;
  #pragma unroll
  for (int i = 0; i < 6; ++i) wf[i * 512 + t] = Wf[i * 512 + t];
  int l = t & 63, w = t >> 6, pl = l & 15, q = l >> 4;
  float bn[6];
  #pragma unroll
  for (int nt = 0; nt < 6; ++nt) bn[nt] = bias[nt * 16 + pl];
  __syncthreads();
  #pragma unroll 1
  for (int g = 0; g < GPB; ++g) {
    int pbase = (blockIdx.x * GPB + g) * 128 + w * 16;
    int p = pbase + pl;                 // this lane's A-row point
    int b = batch[p];
    int x = coords[3 * p], y = coords[3 * p + 1], z = coords[3 * p + 2];
    int s2 = ((b * 64 + (x >> 1)) * 64 + (y >> 1)) * 64 + (z >> 1);
    int s4 = ((b * 32 + (x >> 2)) * 32 + (y >> 2)) * 32 + (z >> 2);
    int s8 = ((b * 16 + (x >> 3)) * 16 + (y >> 3)) * 16 + (z >> 3);
    const uint4* r0 = (const uint4*)(mean0 + (size_t)b * 32);
    const uint4* r2 = (const uint4*)(sums2 + (size_t)s2 * 32);
    const uint4* r4 = (const uint4*)(mean4 + (size_t)s4 * 32);
    const uint4* r8 = (const uint4*)(mean8 + (size_t)s8 * 32);
    uint4 af[8];                        // lane l: A[pl][kt*32 + q*8 .. +7]
    af[0] = r0[q];     af[1] = r0[4 + q];
    af[2] = r2[q];     af[3] = r2[4 + q];
    af[4] = r4[q];     af[5] = r4[4 + q];
    af[6] = r8[q];     af[7] = r8[4 + q];
    uint cv = cnt2[s2];
    float rc = 1.0f / (float)(cv > 1u ? cv : 1u);
    af[2].x = scale_pk(af[2].x, rc); af[2].y = scale_pk(af[2].y, rc);
    af[2].z = scale_pk(af[2].z, rc); af[2].w = scale_pk(af[2].w, rc);
    af[3].x = scale_pk(af[3].x, rc); af[3].y = scale_pk(af[3].y, rc);
    af[3].z = scale_pk(af[3].z, rc); af[3].w = scale_pk(af[3].w, rc);
    f4v acc[6];
    #pragma unroll
    for (int nt = 0; nt < 6; ++nt) acc[nt] = (f4v)0.0f;
    #pragma unroll
    for (int kt = 0; kt < 8; ++kt) {
      s8v afr = __builtin_bit_cast(s8v, af[kt]);
      #pragma unroll
      for (int nt = 0; nt < 6; ++nt) {
        s8v bf = __builtin_bit_cast(s8v, wf[(kt * 6 + nt) * 64 + l]);
        acc[nt] = __builtin_amdgcn_mfma_f32_16x16x32_bf16(afr, bf, acc[nt], 0, 0, 0);
      }
    }
    // D layout: row m = q*4+r (point pbase+m), col = pl (channel nt*16+pl)
    #pragma unroll
    for (int nt = 0; nt < 6; ++nt) {
      #pragma unroll
      for (int r = 0; r < 4; ++r)
        __builtin_nontemporal_store(
            bn[nt] + acc[nt][r],
            &out[(size_t)(pbase + q * 4 + r) * 96 + nt * 16 + pl]);
    }
  }
}

extern "C" void kernel_launch(void* const* d_in, const int* in_sizes, int n_in,
                              void* d_out, int out_size, void* d_ws, size_t ws_size,
                              hipStream_t stream)
{
  const float* feats  = (const float*)d_in[0];
  const int*   coords = (const int*)d_in[1];
  const int*   batch  = (const int*)d_in[2];
  const float* W      = (const float*)d_in[3];
  const float* bias   = (const float*)d_in[4];
  float* out = (float*)d_out;
  char* ws = (char*)d_ws;
  if (ws_size < WS_NEEDED) return;

  uint*  sums2  = (uint*)(ws + OFF_SUMS2);
  uint*  cnt2   = (uint*)(ws + OFF_CNT2);
  float* sums0f = (float*)(ws + OFF_SUMS0F);
  uint*  sums4  = (uint*)(ws + OFF_SUMS4);
  uint*  mean4  = (uint*)(ws + OFF_MEAN4);
  uint*  cnt4   = (uint*)(ws + OFF_CNT4);
  uint*  sums8  = (uint*)(ws + OFF_SUMS8);
  uint*  mean8  = (uint*)(ws + OFF_MEAN8);
  uint*  cnt8   = (uint*)(ws + OFF_CNT8);
  uint*  mean0  = (uint*)(ws + OFF_MEAN0);
  uint*  Wf     = (uint*)(ws + OFF_WF);

  k_zero<<<2048, 256, 0, stream>>>((u4v*)ws);
  k_wf<<<48, 256, 0, stream>>>(W, Wf);
  k_scatter2<<<8192, 256, 0, stream>>>(feats, coords, batch, sums2, cnt2);
  k_down_bf<<<(N4SEG * 32) / 256, 256, 0, stream>>>(sums2, cnt2, sums4, mean4, cnt4, 5, N4SEG);
  k_down_bf<<<(N8SEG * 32) / 256, 256, 0, stream>>>(sums4, cnt4, sums8, mean8, cnt8, 4, N8SEG);
  k_gpart<<<128, 256, 0, stream>>>(sums8, sums0f);
  k_fin0<<<1, 256, 0, stream>>>(sums0f, cnt8, mean0);
  k_final<<<N_PTS / (GPB * 128), 512, 0, stream>>>(
      coords, batch, mean0, sums2, cnt2, mean4, mean8,
      (const uint4*)Wf, bias, out);
}

// Round 6
// 461.590 us; speedup vs baseline: 1.6948x; 1.6948x over previous
//
#include <hip/hip_runtime.h>
#include <stdint.h>

// ---------------------------------------------------------------------------
// SPP: out[n] = b + W @ [mean0(b) | mean2(s2) | mean4(s4) | mean8(s8)]
// v6: v3's known-good k_final (256 thr, VGPR 136, plain stores) + v5's fast
//     k_zero (rocclr fill was 0.57 TB/s). The 512-thr/launch_bounds variant
//     spilled (VGPR 64, FETCH 244MB->1.39GB) -- reverted.
// ---------------------------------------------------------------------------

#define N_PTS   1048576
#define NB      4
#define N2SEG   (NB*64*64*64)   // 1,048,576
#define N4SEG   (NB*32*32*32)   // 131,072
#define N8SEG   (NB*16*16*16)   // 16,384

typedef unsigned int uint;

// workspace offsets (bytes)
#define OFF_SUMS2  ((size_t)0)            // N2SEG*64 bf16 = 134,217,728
#define OFF_CNT2   ((size_t)134217728)    // N2SEG u32     =   4,194,304
#define OFF_SUMS0F ((size_t)138412032)    // 256 f32 (pad 1024)
#define MEMSET_END ((size_t)138413056)    // zeroed region (16B-multiple)
#define OFF_SUMS4  ((size_t)138413056)    // N4SEG*64 bf16 =  16,777,216
#define OFF_MEAN4  ((size_t)155190272)    // N4SEG*64 bf16 =  16,777,216
#define OFF_CNT4   ((size_t)171967488)    // N4SEG u32     =     524,288
#define OFF_SUMS8  ((size_t)172491776)    // N8SEG*64 bf16 =   2,097,152
#define OFF_MEAN8  ((size_t)174588928)    // N8SEG*64 bf16 =   2,097,152
#define OFF_CNT8   ((size_t)176686080)    // N8SEG u32     =      65,536
#define OFF_MEAN0  ((size_t)176751616)    // 4*32 u32 (pad 1024)
#define OFF_WF     ((size_t)176752640)    // 48 KB frag-ready W
#define WS_NEEDED  ((size_t)176801792)

typedef short s8v __attribute__((ext_vector_type(8)));   // 8 bf16 (4 VGPR)
typedef float f4v __attribute__((ext_vector_type(4)));   // MFMA C/D
typedef uint  u4v __attribute__((ext_vector_type(4)));   // NT-store-friendly

__device__ __forceinline__ uint pack_bf16x2(float a, float b) {
  uint ua = __float_as_uint(a), ub = __float_as_uint(b);
  ua = (ua + 0x7fffu + ((ua >> 16) & 1u)) >> 16;   // RNE
  ub = (ub + 0x7fffu + ((ub >> 16) & 1u)) >> 16;
  return (ub << 16) | ua;
}
__device__ __forceinline__ float bflo(uint u) { return __uint_as_float(u << 16); }
__device__ __forceinline__ float bfhi(uint u) { return __uint_as_float(u & 0xffff0000u); }

__device__ __forceinline__ uint scale_pk(uint u, float rc) {
  return pack_bf16x2(bflo(u) * rc, bfhi(u) * rc);
}

// ---- fast zero of the atomic-accumulated region (16B granularity)
#define ZERO_U4 (MEMSET_END / 16)
__global__ __launch_bounds__(256) void k_zero(u4v* __restrict__ p) {
  u4v z = (u4v)0u;
  size_t stride = (size_t)gridDim.x * 256;
  for (size_t i = blockIdx.x * 256ull + threadIdx.x; i < ZERO_U4; i += stride)
    __builtin_nontemporal_store(z, &p[i]);
}

// ---- frag-ready W: Wf[((kt*6+nt)*64+l)*4+d] = pack(W[n][k], W[n][k+1])
//      n = nt*16+(l&15), k = kt*32+(l>>4)*8+2d   (B[k][n] = W[n][k])
__global__ __launch_bounds__(256) void k_wf(const float* __restrict__ W,
                                            uint* __restrict__ Wf) {
  int idx = blockIdx.x * 256 + threadIdx.x;        // < 12288
  int d = idx & 3, l = (idx >> 2) & 63, ktnt = idx >> 8;
  int kt = ktnt / 6, nt = ktnt - kt * 6;
  int n = nt * 16 + (l & 15);
  int k = kt * 32 + (l >> 4) * 8 + d * 2;
  Wf[idx] = pack_bf16x2(W[n * 256 + k], W[n * 256 + k + 1]);
}

// ---- scatter: 2 points per wave, lane = (half, channel-pair), pk-bf16 atomics
__global__ __launch_bounds__(256) void k_scatter2(
    const float* __restrict__ feats, const int* __restrict__ coords,
    const int* __restrict__ batch, uint* __restrict__ sums2,
    uint* __restrict__ cnt2)
{
  int l = threadIdx.x & 63;
  int c2 = l & 31, half = l >> 5;
  int wid = (blockIdx.x * 256 + threadIdx.x) >> 6;
  int nw = (gridDim.x * 256) >> 6;
  for (int p0 = wid * 2; p0 < N_PTS; p0 += nw * 2) {
    int p = p0 + half;
    float2 f = ((const float2*)feats)[(size_t)p * 32 + c2];
    int b = batch[p];
    int x = coords[3 * p], y = coords[3 * p + 1], z = coords[3 * p + 2];
    int s2 = ((b * 64 + (x >> 1)) * 64 + (y >> 1)) * 64 + (z >> 1);
    uint pk = pack_bf16x2(f.x, f.y);
    uint64_t addr = (uint64_t)(uintptr_t)(sums2 + (size_t)s2 * 32 + c2);
    asm volatile("global_atomic_pk_add_bf16 %0, %1, off"
                 :: "v"(addr), "v"(pk) : "memory");
    if (c2 == 0) atomicAdd(&cnt2[s2], 1u);
  }
}

// ---- 8-child tree reduction; writes raw sums (next level), pre-scaled mean,
//      and cnt. thread = (sc, c2)
__global__ __launch_bounds__(256) void k_down_bf(
    const uint* __restrict__ sumsF, const uint* __restrict__ cntF,
    uint* __restrict__ sumsC, uint* __restrict__ meanC,
    uint* __restrict__ cntC, int lgC, int nC)
{
  int tid = blockIdx.x * 256 + threadIdx.x;
  int sc = tid >> 5, c2 = tid & 31;
  if (sc >= nC) return;
  int CG = 1 << lgC, FG = CG << 1;
  int b = sc >> (3 * lgC);
  int r = sc & ((1 << (3 * lgC)) - 1);
  int x = r >> (2 * lgC), y = (r >> lgC) & (CG - 1), z = r & (CG - 1);
  float sx = 0.f, sy = 0.f;
  uint cn = 0;
  #pragma unroll
  for (int dx = 0; dx < 2; ++dx)
    #pragma unroll
    for (int dy = 0; dy < 2; ++dy)
      #pragma unroll
      for (int dz = 0; dz < 2; ++dz) {
        int sf = ((b * FG + 2 * x + dx) * FG + (2 * y + dy)) * FG + (2 * z + dz);
        uint u = sumsF[(size_t)sf * 32 + c2];
        sx += bflo(u); sy += bfhi(u);
        cn += cntF[sf];                       // same addr across 32 lanes: L1 broadcast
      }
  sumsC[(size_t)sc * 32 + c2] = pack_bf16x2(sx, sy);
  float rc = 1.0f / (float)(cn > 1u ? cn : 1u);
  meanC[(size_t)sc * 32 + c2] = pack_bf16x2(sx * rc, sy * rc);
  if (c2 == 0) cntC[sc] = cn;
}

// ---- per-batch global partial reduce (32 blocks/batch), f32 atomics
__global__ __launch_bounds__(256) void k_gpart(
    const uint* __restrict__ sums8, float* __restrict__ sums0f)
{
  __shared__ float2 red[8][32];
  int b = blockIdx.x >> 5, chunk = blockIdx.x & 31;
  int t = threadIdx.x, c2 = t & 31, g = t >> 5;
  float sx = 0.f, sy = 0.f;
  for (int i = g; i < 128; i += 8) {
    uint u = sums8[(size_t)(b * 4096 + chunk * 128 + i) * 32 + c2];
    sx += bflo(u); sy += bfhi(u);
  }
  red[g][c2] = make_float2(sx, sy);
  __syncthreads();
  if (g == 0) {
    float ax = 0.f, ay = 0.f;
    #pragma unroll
    for (int i = 0; i < 8; ++i) { ax += red[i][c2].x; ay += red[i][c2].y; }
    unsafeAtomicAdd(&sums0f[b * 64 + 2 * c2], ax);
    unsafeAtomicAdd(&sums0f[b * 64 + 2 * c2 + 1], ay);
  }
}

// ---- finalize level 0: cnt0 from cnt8, mean0 = sums0f/cnt0 (bf16, pre-scaled)
__global__ __launch_bounds__(256) void k_fin0(
    const float* __restrict__ sums0f, const uint* __restrict__ cnt8,
    uint* __restrict__ mean0)
{
  __shared__ uint redc[256];
  __shared__ float rcs[NB];
  int t = threadIdx.x;
  uint cn = 0;
  for (int i = 0; i < 64; ++i) cn += cnt8[t * 64 + i];
  redc[t] = cn;
  __syncthreads();
  if (t < NB) {
    uint s = 0;
    for (int i = 0; i < 64; ++i) s += redc[t * 64 + i];
    rcs[t] = 1.0f / (float)(s > 1u ? s : 1u);
  }
  __syncthreads();
  if (t < 128) {
    int b = t >> 5, c2 = t & 31;
    float rc = rcs[b];
    mean0[b * 32 + c2] =
        pack_bf16x2(sums0f[b * 64 + 2 * c2] * rc, sums0f[b * 64 + 2 * c2 + 1] * rc);
  }
}

// ---- fused gather-GEMM (v3 known-good): wave = 16 points; A gathered
//      (level-2 scaled in-register, others pre-scaled); B frag-ready in LDS.
#define GPB 8
__global__ __launch_bounds__(256) void k_final(
    const int* __restrict__ coords, const int* __restrict__ batch,
    const uint* __restrict__ mean0,
    const uint* __restrict__ sums2, const uint* __restrict__ cnt2,
    const uint* __restrict__ mean4, const uint* __restrict__ mean8,
    const uint4* __restrict__ Wf, const float* __restrict__ bias,
    float* __restrict__ out)
{
  __shared__ uint4 wf[3072];   // 48 KB frag-ready W
  int t = threadIdx.x;
  #pragma unroll
  for (int i = 0; i < 12; ++i) wf[i * 256 + t] = Wf[i * 256 + t];
  __syncthreads();
  int l = t & 63, w = t >> 6, pl = l & 15, q = l >> 4;
  #pragma unroll 1
  for (int g = 0; g < GPB; ++g) {
    int pbase = (blockIdx.x * GPB + g) * 64 + w * 16;
    int p = pbase + pl;                 // this lane's A-row point
    int b = batch[p];
    int x = coords[3 * p], y = coords[3 * p + 1], z = coords[3 * p + 2];
    int s2 = ((b * 64 + (x >> 1)) * 64 + (y >> 1)) * 64 + (z >> 1);
    int s4 = ((b * 32 + (x >> 2)) * 32 + (y >> 2)) * 32 + (z >> 2);
    int s8 = ((b * 16 + (x >> 3)) * 16 + (y >> 3)) * 16 + (z >> 3);
    const uint4* r0 = (const uint4*)(mean0 + (size_t)b * 32);
    const uint4* r2 = (const uint4*)(sums2 + (size_t)s2 * 32);
    const uint4* r4 = (const uint4*)(mean4 + (size_t)s4 * 32);
    const uint4* r8 = (const uint4*)(mean8 + (size_t)s8 * 32);
    uint4 af[8];                        // lane l: A[pl][kt*32 + q*8 .. +7]
    af[0] = r0[q];     af[1] = r0[4 + q];
    af[2] = r2[q];     af[3] = r2[4 + q];
    af[4] = r4[q];     af[5] = r4[4 + q];
    af[6] = r8[q];     af[7] = r8[4 + q];
    uint cv = cnt2[s2];
    float rc = 1.0f / (float)(cv > 1u ? cv : 1u);
    af[2].x = scale_pk(af[2].x, rc); af[2].y = scale_pk(af[2].y, rc);
    af[2].z = scale_pk(af[2].z, rc); af[2].w = scale_pk(af[2].w, rc);
    af[3].x = scale_pk(af[3].x, rc); af[3].y = scale_pk(af[3].y, rc);
    af[3].z = scale_pk(af[3].z, rc); af[3].w = scale_pk(af[3].w, rc);
    f4v acc[6];
    #pragma unroll
    for (int nt = 0; nt < 6; ++nt) acc[nt] = (f4v)0.0f;
    #pragma unroll
    for (int kt = 0; kt < 8; ++kt) {
      s8v afr = __builtin_bit_cast(s8v, af[kt]);
      #pragma unroll
      for (int nt = 0; nt < 6; ++nt) {
        s8v bf = __builtin_bit_cast(s8v, wf[(kt * 6 + nt) * 64 + l]);
        acc[nt] = __builtin_amdgcn_mfma_f32_16x16x32_bf16(afr, bf, acc[nt], 0, 0, 0);
      }
    }
    // D layout: row m = q*4+r (point pbase+m), col = pl (channel nt*16+pl)
    #pragma unroll
    for (int nt = 0; nt < 6; ++nt) {
      float bn = bias[nt * 16 + pl];
      #pragma unroll
      for (int r = 0; r < 4; ++r)
        out[(size_t)(pbase + q * 4 + r) * 96 + nt * 16 + pl] = bn + acc[nt][r];
    }
  }
}

extern "C" void kernel_launch(void* const* d_in, const int* in_sizes, int n_in,
                              void* d_out, int out_size, void* d_ws, size_t ws_size,
                              hipStream_t stream)
{
  const float* feats  = (const float*)d_in[0];
  const int*   coords = (const int*)d_in[1];
  const int*   batch  = (const int*)d_in[2];
  const float* W      = (const float*)d_in[3];
  const float* bias   = (const float*)d_in[4];
  float* out = (float*)d_out;
  char* ws = (char*)d_ws;
  if (ws_size < WS_NEEDED) return;

  uint*  sums2  = (uint*)(ws + OFF_SUMS2);
  uint*  cnt2   = (uint*)(ws + OFF_CNT2);
  float* sums0f = (float*)(ws + OFF_SUMS0F);
  uint*  sums4  = (uint*)(ws + OFF_SUMS4);
  uint*  mean4  = (uint*)(ws + OFF_MEAN4);
  uint*  cnt4   = (uint*)(ws + OFF_CNT4);
  uint*  sums8  = (uint*)(ws + OFF_SUMS8);
  uint*  mean8  = (uint*)(ws + OFF_MEAN8);
  uint*  cnt8   = (uint*)(ws + OFF_CNT8);
  uint*  mean0  = (uint*)(ws + OFF_MEAN0);
  uint*  Wf     = (uint*)(ws + OFF_WF);

  k_zero<<<2048, 256, 0, stream>>>((u4v*)ws);
  k_wf<<<48, 256, 0, stream>>>(W, Wf);
  k_scatter2<<<8192, 256, 0, stream>>>(feats, coords, batch, sums2, cnt2);
  k_down_bf<<<(N4SEG * 32) / 256, 256, 0, stream>>>(sums2, cnt2, sums4, mean4, cnt4, 5, N4SEG);
  k_down_bf<<<(N8SEG * 32) / 256, 256, 0, stream>>>(sums4, cnt4, sums8, mean8, cnt8, 4, N8SEG);
  k_gpart<<<128, 256, 0, stream>>>(sums8, sums0f);
  k_fin0<<<1, 256, 0, stream>>>(sums0f, cnt8, mean0);
  k_final<<<N_PTS / (GPB * 64), 256, 0, stream>>>(
      coords, batch, mean0, sums2, cnt2, mean4, mean8,
      (const uint4*)Wf, bias, out);
}

// Round 7
// 428.203 us; speedup vs baseline: 1.8270x; 1.0780x over previous
//
#include <hip/hip_runtime.h>
#include <stdint.h>

// ---------------------------------------------------------------------------
// SPP: out[n] = b + W @ [mean0(b) | mean2(s2) | mean4(s4) | mean8(s8)]
// v7: = v6 + (a) depth-2 software pipeline of k_final's gathers (dual-buffered
//     af/cnt, one ws-base + const dword offsets to pay the VGPR bill) and
//     (b) scatter atomic without "memory" clobber (lets compiler pipeline).
// ---------------------------------------------------------------------------

#define N_PTS   1048576
#define NB      4
#define N2SEG   (NB*64*64*64)   // 1,048,576
#define N4SEG   (NB*32*32*32)   // 131,072
#define N8SEG   (NB*16*16*16)   // 16,384

typedef unsigned int uint;

// workspace offsets (bytes)
#define OFF_SUMS2  ((size_t)0)            // N2SEG*64 bf16 = 134,217,728
#define OFF_CNT2   ((size_t)134217728)    // N2SEG u32     =   4,194,304
#define OFF_SUMS0F ((size_t)138412032)    // 256 f32 (pad 1024)
#define MEMSET_END ((size_t)138413056)    // zeroed region (16B-multiple)
#define OFF_SUMS4  ((size_t)138413056)    // N4SEG*64 bf16 =  16,777,216
#define OFF_MEAN4  ((size_t)155190272)    // N4SEG*64 bf16 =  16,777,216
#define OFF_CNT4   ((size_t)171967488)    // N4SEG u32     =     524,288
#define OFF_SUMS8  ((size_t)172491776)    // N8SEG*64 bf16 =   2,097,152
#define OFF_MEAN8  ((size_t)174588928)    // N8SEG*64 bf16 =   2,097,152
#define OFF_CNT8   ((size_t)176686080)    // N8SEG u32     =      65,536
#define OFF_MEAN0  ((size_t)176751616)    // 4*32 u32 (pad 1024)
#define OFF_WF     ((size_t)176752640)    // 48 KB frag-ready W
#define WS_NEEDED  ((size_t)176801792)

// dword offsets into workspace (for k_final's single-base addressing)
#define D_S2 0u
#define D_C2 ((uint)(OFF_CNT2 / 4))
#define D_M4 ((uint)(OFF_MEAN4 / 4))
#define D_M8 ((uint)(OFF_MEAN8 / 4))
#define D_M0 ((uint)(OFF_MEAN0 / 4))

typedef short s8v __attribute__((ext_vector_type(8)));   // 8 bf16 (4 VGPR)
typedef float f4v __attribute__((ext_vector_type(4)));   // MFMA C/D
typedef uint  u4v __attribute__((ext_vector_type(4)));   // NT-store-friendly

__device__ __forceinline__ uint pack_bf16x2(float a, float b) {
  uint ua = __float_as_uint(a), ub = __float_as_uint(b);
  ua = (ua + 0x7fffu + ((ua >> 16) & 1u)) >> 16;   // RNE
  ub = (ub + 0x7fffu + ((ub >> 16) & 1u)) >> 16;
  return (ub << 16) | ua;
}
__device__ __forceinline__ float bflo(uint u) { return __uint_as_float(u << 16); }
__device__ __forceinline__ float bfhi(uint u) { return __uint_as_float(u & 0xffff0000u); }

__device__ __forceinline__ uint scale_pk(uint u, float rc) {
  return pack_bf16x2(bflo(u) * rc, bfhi(u) * rc);
}

// ---- fast zero of the atomic-accumulated region (16B granularity)
#define ZERO_U4 (MEMSET_END / 16)
__global__ __launch_bounds__(256) void k_zero(u4v* __restrict__ p) {
  u4v z = (u4v)0u;
  size_t stride = (size_t)gridDim.x * 256;
  for (size_t i = blockIdx.x * 256ull + threadIdx.x; i < ZERO_U4; i += stride)
    __builtin_nontemporal_store(z, &p[i]);
}

// ---- frag-ready W: Wf[((kt*6+nt)*64+l)*4+d] = pack(W[n][k], W[n][k+1])
//      n = nt*16+(l&15), k = kt*32+(l>>4)*8+2d   (B[k][n] = W[n][k])
__global__ __launch_bounds__(256) void k_wf(const float* __restrict__ W,
                                            uint* __restrict__ Wf) {
  int idx = blockIdx.x * 256 + threadIdx.x;        // < 12288
  int d = idx & 3, l = (idx >> 2) & 63, ktnt = idx >> 8;
  int kt = ktnt / 6, nt = ktnt - kt * 6;
  int n = nt * 16 + (l & 15);
  int k = kt * 32 + (l >> 4) * 8 + d * 2;
  Wf[idx] = pack_bf16x2(W[n * 256 + k], W[n * 256 + k + 1]);
}

// ---- scatter: 2 points per wave, lane = (half, channel-pair), pk-bf16 atomics
//      NOTE: no "memory" clobber on the atomic -> compiler may pipeline
//      iterations (nothing in-kernel reads sums2; ordering is only needed at
//      kernel boundary).
__global__ __launch_bounds__(256) void k_scatter2(
    const float* __restrict__ feats, const int* __restrict__ coords,
    const int* __restrict__ batch, uint* __restrict__ sums2,
    uint* __restrict__ cnt2)
{
  int l = threadIdx.x & 63;
  int c2 = l & 31, half = l >> 5;
  int wid = (blockIdx.x * 256 + threadIdx.x) >> 6;
  int nw = (gridDim.x * 256) >> 6;
  for (int p0 = wid * 2; p0 < N_PTS; p0 += nw * 2) {
    int p = p0 + half;
    float2 f = ((const float2*)feats)[(size_t)p * 32 + c2];
    int b = batch[p];
    int x = coords[3 * p], y = coords[3 * p + 1], z = coords[3 * p + 2];
    int s2 = ((b * 64 + (x >> 1)) * 64 + (y >> 1)) * 64 + (z >> 1);
    uint pk = pack_bf16x2(f.x, f.y);
    uint64_t addr = (uint64_t)(uintptr_t)(sums2 + (size_t)s2 * 32 + c2);
    asm volatile("global_atomic_pk_add_bf16 %0, %1, off"
                 :: "v"(addr), "v"(pk));
    if (c2 == 0) atomicAdd(&cnt2[s2], 1u);
  }
}

// ---- 8-child tree reduction; writes raw sums (next level), pre-scaled mean,
//      and cnt. thread = (sc, c2)
__global__ __launch_bounds__(256) void k_down_bf(
    const uint* __restrict__ sumsF, const uint* __restrict__ cntF,
    uint* __restrict__ sumsC, uint* __restrict__ meanC,
    uint* __restrict__ cntC, int lgC, int nC)
{
  int tid = blockIdx.x * 256 + threadIdx.x;
  int sc = tid >> 5, c2 = tid & 31;
  if (sc >= nC) return;
  int CG = 1 << lgC, FG = CG << 1;
  int b = sc >> (3 * lgC);
  int r = sc & ((1 << (3 * lgC)) - 1);
  int x = r >> (2 * lgC), y = (r >> lgC) & (CG - 1), z = r & (CG - 1);
  float sx = 0.f, sy = 0.f;
  uint cn = 0;
  #pragma unroll
  for (int dx = 0; dx < 2; ++dx)
    #pragma unroll
    for (int dy = 0; dy < 2; ++dy)
      #pragma unroll
      for (int dz = 0; dz < 2; ++dz) {
        int sf = ((b * FG + 2 * x + dx) * FG + (2 * y + dy)) * FG + (2 * z + dz);
        uint u = sumsF[(size_t)sf * 32 + c2];
        sx += bflo(u); sy += bfhi(u);
        cn += cntF[sf];                       // same addr across 32 lanes: L1 broadcast
      }
  sumsC[(size_t)sc * 32 + c2] = pack_bf16x2(sx, sy);
  float rc = 1.0f / (float)(cn > 1u ? cn : 1u);
  meanC[(size_t)sc * 32 + c2] = pack_bf16x2(sx * rc, sy * rc);
  if (c2 == 0) cntC[sc] = cn;
}

// ---- per-batch global partial reduce (32 blocks/batch), f32 atomics
__global__ __launch_bounds__(256) void k_gpart(
    const uint* __restrict__ sums8, float* __restrict__ sums0f)
{
  __shared__ float2 red[8][32];
  int b = blockIdx.x >> 5, chunk = blockIdx.x & 31;
  int t = threadIdx.x, c2 = t & 31, g = t >> 5;
  float sx = 0.f, sy = 0.f;
  for (int i = g; i < 128; i += 8) {
    uint u = sums8[(size_t)(b * 4096 + chunk * 128 + i) * 32 + c2];
    sx += bflo(u); sy += bfhi(u);
  }
  red[g][c2] = make_float2(sx, sy);
  __syncthreads();
  if (g == 0) {
    float ax = 0.f, ay = 0.f;
    #pragma unroll
    for (int i = 0; i < 8; ++i) { ax += red[i][c2].x; ay += red[i][c2].y; }
    unsafeAtomicAdd(&sums0f[b * 64 + 2 * c2], ax);
    unsafeAtomicAdd(&sums0f[b * 64 + 2 * c2 + 1], ay);
  }
}

// ---- finalize level 0: cnt0 from cnt8, mean0 = sums0f/cnt0 (bf16, pre-scaled)
__global__ __launch_bounds__(256) void k_fin0(
    const float* __restrict__ sums0f, const uint* __restrict__ cnt8,
    uint* __restrict__ mean0)
{
  __shared__ uint redc[256];
  __shared__ float rcs[NB];
  int t = threadIdx.x;
  uint cn = 0;
  for (int i = 0; i < 64; ++i) cn += cnt8[t * 64 + i];
  redc[t] = cn;
  __syncthreads();
  if (t < NB) {
    uint s = 0;
    for (int i = 0; i < 64; ++i) s += redc[t * 64 + i];
    rcs[t] = 1.0f / (float)(s > 1u ? s : 1u);
  }
  __syncthreads();
  if (t < 128) {
    int b = t >> 5, c2 = t & 31;
    float rc = rcs[b];
    mean0[b * 32 + c2] =
        pack_bf16x2(sums0f[b * 64 + 2 * c2] * rc, sums0f[b * 64 + 2 * c2 + 1] * rc);
  }
}

// ---- fused gather-GEMM, depth-2 pipelined: while MFMAing iteration g, the
//      9 gather loads for g+1 are already in flight. Single ws base pointer +
//      compile-time dword offsets to keep VGPR <= ~168 (3 waves/SIMD).
#define GPB 8
__global__ __launch_bounds__(256) void k_final(
    const int* __restrict__ coords, const int* __restrict__ batch,
    const uint* __restrict__ wsb,     // workspace base, dword-indexed
    const uint4* __restrict__ Wf, const float* __restrict__ bias,
    float* __restrict__ out)
{
  __shared__ uint4 wf[3072];   // 48 KB frag-ready W
  int t = threadIdx.x;
  #pragma unroll
  for (int i = 0; i < 12; ++i) wf[i * 256 + t] = Wf[i * 256 + t];
  int l = t & 63, w = t >> 6, pl = l & 15, q = l >> 4;
  float bn[6];
  #pragma unroll
  for (int nt = 0; nt < 6; ++nt) bn[nt] = bias[nt * 16 + pl];
  __syncthreads();

  uint4 afc[8];   // current iteration's A fragments
  uint cvc;       // current cnt2
  {
    int p = blockIdx.x * (GPB * 64) + w * 16 + pl;   // g = 0
    int b = batch[p];
    int x = coords[3 * p], y = coords[3 * p + 1], z = coords[3 * p + 2];
    int s2 = ((b * 64 + (x >> 1)) * 64 + (y >> 1)) * 64 + (z >> 1);
    int s4 = ((b * 32 + (x >> 2)) * 32 + (y >> 2)) * 32 + (z >> 2);
    int s8 = ((b * 16 + (x >> 3)) * 16 + (y >> 3)) * 16 + (z >> 3);
    const uint4* a0 = (const uint4*)(wsb + D_M0 + b * 32);
    const uint4* a2 = (const uint4*)(wsb + D_S2 + s2 * 32);
    const uint4* a4 = (const uint4*)(wsb + D_M4 + s4 * 32);
    const uint4* a8 = (const uint4*)(wsb + D_M8 + s8 * 32);
    afc[0] = a0[q];     afc[1] = a0[4 + q];
    afc[2] = a2[q];     afc[3] = a2[4 + q];
    afc[4] = a4[q];     afc[5] = a4[4 + q];
    afc[6] = a8[q];     afc[7] = a8[4 + q];
    cvc = wsb[D_C2 + s2];
  }

  #pragma unroll 1
  for (int g = 0; g < GPB; ++g) {
    uint4 afn[8];
    uint cvn = 0;
    if (g + 1 < GPB) {   // issue next iteration's gathers first
      int p = blockIdx.x * (GPB * 64) + (g + 1) * 64 + w * 16 + pl;
      int b = batch[p];
      int x = coords[3 * p], y = coords[3 * p + 1], z = coords[3 * p + 2];
      int s2 = ((b * 64 + (x >> 1)) * 64 + (y >> 1)) * 64 + (z >> 1);
      int s4 = ((b * 32 + (x >> 2)) * 32 + (y >> 2)) * 32 + (z >> 2);
      int s8 = ((b * 16 + (x >> 3)) * 16 + (y >> 3)) * 16 + (z >> 3);
      const uint4* a0 = (const uint4*)(wsb + D_M0 + b * 32);
      const uint4* a2 = (const uint4*)(wsb + D_S2 + s2 * 32);
      const uint4* a4 = (const uint4*)(wsb + D_M4 + s4 * 32);
      const uint4* a8 = (const uint4*)(wsb + D_M8 + s8 * 32);
      afn[0] = a0[q];     afn[1] = a0[4 + q];
      afn[2] = a2[q];     afn[3] = a2[4 + q];
      afn[4] = a4[q];     afn[5] = a4[4 + q];
      afn[6] = a8[q];     afn[7] = a8[4 + q];
      cvn = wsb[D_C2 + s2];
    }

    // process current
    float rc = 1.0f / (float)(cvc > 1u ? cvc : 1u);
    afc[2].x = scale_pk(afc[2].x, rc); afc[2].y = scale_pk(afc[2].y, rc);
    afc[2].z = scale_pk(afc[2].z, rc); afc[2].w = scale_pk(afc[2].w, rc);
    afc[3].x = scale_pk(afc[3].x, rc); afc[3].y = scale_pk(afc[3].y, rc);
    afc[3].z = scale_pk(afc[3].z, rc); afc[3].w = scale_pk(afc[3].w, rc);
    f4v acc[6];
    #pragma unroll
    for (int nt = 0; nt < 6; ++nt) acc[nt] = (f4v)0.0f;
    #pragma unroll
    for (int kt = 0; kt < 8; ++kt) {
      s8v afr = __builtin_bit_cast(s8v, afc[kt]);
      #pragma unroll
      for (int nt = 0; nt < 6; ++nt) {
        s8v bf = __builtin_bit_cast(s8v, wf[(kt * 6 + nt) * 64 + l]);
        acc[nt] = __builtin_amdgcn_mfma_f32_16x16x32_bf16(afr, bf, acc[nt], 0, 0, 0);
      }
    }
    // D layout: row m = q*4+r (point pbase+m), col = pl (channel nt*16+pl)
    int pbase = blockIdx.x * (GPB * 64) + g * 64 + w * 16;
    float* ob = out + (size_t)(pbase + q * 4) * 96 + pl;
    #pragma unroll
    for (int nt = 0; nt < 6; ++nt)
      #pragma unroll
      for (int r = 0; r < 4; ++r)
        ob[r * 96 + nt * 16] = bn[nt] + acc[nt][r];

    // rotate pipeline
    #pragma unroll
    for (int i = 0; i < 8; ++i) afc[i] = afn[i];
    cvc = cvn;
  }
}

extern "C" void kernel_launch(void* const* d_in, const int* in_sizes, int n_in,
                              void* d_out, int out_size, void* d_ws, size_t ws_size,
                              hipStream_t stream)
{
  const float* feats  = (const float*)d_in[0];
  const int*   coords = (const int*)d_in[1];
  const int*   batch  = (const int*)d_in[2];
  const float* W      = (const float*)d_in[3];
  const float* bias   = (const float*)d_in[4];
  float* out = (float*)d_out;
  char* ws = (char*)d_ws;
  if (ws_size < WS_NEEDED) return;

  uint*  sums2  = (uint*)(ws + OFF_SUMS2);
  uint*  cnt2   = (uint*)(ws + OFF_CNT2);
  float* sums0f = (float*)(ws + OFF_SUMS0F);
  uint*  sums4  = (uint*)(ws + OFF_SUMS4);
  uint*  mean4  = (uint*)(ws + OFF_MEAN4);
  uint*  cnt4   = (uint*)(ws + OFF_CNT4);
  uint*  sums8  = (uint*)(ws + OFF_SUMS8);
  uint*  mean8  = (uint*)(ws + OFF_MEAN8);
  uint*  cnt8   = (uint*)(ws + OFF_CNT8);
  uint*  mean0  = (uint*)(ws + OFF_MEAN0);
  uint*  Wf     = (uint*)(ws + OFF_WF);

  k_zero<<<2048, 256, 0, stream>>>((u4v*)ws);
  k_wf<<<48, 256, 0, stream>>>(W, Wf);
  k_scatter2<<<8192, 256, 0, stream>>>(feats, coords, batch, sums2, cnt2);
  k_down_bf<<<(N4SEG * 32) / 256, 256, 0, stream>>>(sums2, cnt2, sums4, mean4, cnt4, 5, N4SEG);
  k_down_bf<<<(N8SEG * 32) / 256, 256, 0, stream>>>(sums4, cnt4, sums8, mean8, cnt8, 4, N8SEG);
  k_gpart<<<128, 256, 0, stream>>>(sums8, sums0f);
  k_fin0<<<1, 256, 0, stream>>>(sums0f, cnt8, mean0);
  k_final<<<N_PTS / (GPB * 64), 256, 0, stream>>>(
      coords, batch, (const uint*)ws, (const uint4*)Wf, bias, out);
}